// Round 2
// baseline (434.207 us; speedup 1.0000x reference)
//
#include <hip/hip_runtime.h>
#include <type_traits>

typedef __bf16 bf16;
typedef __attribute__((ext_vector_type(8))) __bf16 bf16x8;
typedef __attribute__((ext_vector_type(4))) float f32x4;

constexpr int Bc = 4, Tc = 2048, Cc = 1024, Hc = 16;
constexpr int Mrows = Bc * Tc;   // 8192
constexpr int N3 = 3 * Cc;       // 3072

#define GLOAD(gp, lp)                                                          \
  __builtin_amdgcn_global_load_lds(                                           \
      (const __attribute__((address_space(1))) void*)(gp),                     \
      (__attribute__((address_space(3))) void*)(lp), 16, 0, 0)

// ---------------- cast fp32 -> bf16, 8 elems/thread ----------------
__global__ __launch_bounds__(256) void cast_bf16_kernel(
    const float* __restrict__ in, bf16* __restrict__ out, int n8) {
  int i = blockIdx.x * blockDim.x + threadIdx.x;
  int stride = gridDim.x * blockDim.x;
  for (; i < n8; i += stride) {
    const float4* p = (const float4*)(in + (long)i * 8);
    float4 a = p[0], b = p[1];
    bf16x8 v;
    v[0] = (bf16)a.x; v[1] = (bf16)a.y; v[2] = (bf16)a.z; v[3] = (bf16)a.w;
    v[4] = (bf16)b.x; v[5] = (bf16)b.y; v[6] = (bf16)b.z; v[7] = (bf16)b.w;
    *(bf16x8*)(out + (long)i * 8) = v;
  }
}

// ---------------- transpose + cast: in[rows][cols] f32 -> out[cols][rows] bf16
__global__ __launch_bounds__(256) void transpose_cast_kernel(
    const float* __restrict__ in, bf16* __restrict__ out, int rows, int cols) {
  __shared__ float tile[32][33];
  int tx = threadIdx.x, ty = threadIdx.y;
  int r0 = blockIdx.y * 32, c0 = blockIdx.x * 32;
#pragma unroll
  for (int i = 0; i < 4; i++)
    tile[ty + 8 * i][tx] = in[(long)(r0 + ty + 8 * i) * cols + c0 + tx];
  __syncthreads();
#pragma unroll
  for (int i = 0; i < 4; i++)
    out[(long)(c0 + ty + 8 * i) * rows + r0 + tx] = (bf16)tile[tx][ty + 8 * i];
}

// ---------------- transpose V part of QKV: Y[.,2048+h*64+d] -> Vt[bh][d][t]
__global__ __launch_bounds__(256) void transpose_v_kernel(
    const bf16* __restrict__ Y, bf16* __restrict__ Vt) {
  __shared__ bf16 tile[32][33];
  int tx = threadIdx.x, ty = threadIdx.y;
  int t0 = blockIdx.x * 32;
  int d0 = blockIdx.y * 32;
  int bh = blockIdx.z;
  int b = bh >> 4, h = bh & 15;
  const bf16* src = Y + (long)(b * Tc) * N3 + 2 * Cc + h * 64;
#pragma unroll
  for (int i = 0; i < 4; i++)
    tile[ty + 8 * i][tx] = src[(long)(t0 + ty + 8 * i) * N3 + d0 + tx];
  __syncthreads();
  bf16* dst = Vt + (long)bh * 64 * Tc;
#pragma unroll
  for (int i = 0; i < 4; i++)
    dst[(long)(d0 + ty + 8 * i) * Tc + t0 + tx] = tile[tx][ty + 8 * i];
}

// ---------------- GEMM: C[M,N] = A[M,K](bf16) * Bt[N,K]^T + bias, m97 structure
template <typename OutT>
__global__ __launch_bounds__(256) void gemm_bt_kernel(
    const bf16* __restrict__ A, const bf16* __restrict__ Bt,
    const float* __restrict__ bias, OutT* __restrict__ Cout, int M, int N,
    int K) {
  __shared__ __align__(16) bf16 Alds[128 * 32];
  __shared__ __align__(16) bf16 Blds[128 * 32];
  const int tid = threadIdx.x;
  const int w = tid >> 6, l = tid & 63;
  const int m0 = blockIdx.x * 128, n0 = blockIdx.y * 128;
  const int wr = w >> 1, wc = w & 1;
  f32x4 acc[4][4] = {};
  const int arow = tid >> 2, achunk = tid & 3;
  const bf16* Ag = A + (long)(m0 + arow) * K + achunk * 8;
  const bf16* Bg = Bt + (long)(n0 + arow) * K + achunk * 8;
  char* AldsB = (char*)Alds;
  char* BldsB = (char*)Blds;
  const int wbase = w * 1024;  // wave-uniform LDS byte base

  for (int k0 = 0; k0 < K; k0 += 32) {
    __syncthreads();
    GLOAD(Ag + k0, AldsB + wbase);
    GLOAD(Ag + k0 + (long)64 * K, AldsB + wbase + 4096);
    GLOAD(Bg + k0, BldsB + wbase);
    GLOAD(Bg + k0 + (long)64 * K, BldsB + wbase + 4096);
    __syncthreads();
    const int kk = (l >> 4) * 8;
    bf16x8 af[4], bfr[4];
#pragma unroll
    for (int mi = 0; mi < 4; mi++)
      af[mi] = *(const bf16x8*)(AldsB +
                                ((wr * 64 + mi * 16 + (l & 15)) * 32 + kk) * 2);
#pragma unroll
    for (int ni = 0; ni < 4; ni++)
      bfr[ni] = *(const bf16x8*)(BldsB +
                                 ((wc * 64 + ni * 16 + (l & 15)) * 32 + kk) * 2);
#pragma unroll
    for (int mi = 0; mi < 4; mi++)
#pragma unroll
      for (int ni = 0; ni < 4; ni++)
        acc[mi][ni] = __builtin_amdgcn_mfma_f32_16x16x32_bf16(
            af[mi], bfr[ni], acc[mi][ni], 0, 0, 0);
  }
  const int rrow = (l >> 4) * 4, col = l & 15;
#pragma unroll
  for (int mi = 0; mi < 4; mi++) {
#pragma unroll
    for (int ni = 0; ni < 4; ni++) {
      int gcol = n0 + wc * 64 + ni * 16 + col;
      float bv = bias[gcol];
#pragma unroll
      for (int i = 0; i < 4; i++) {
        int grow = m0 + wr * 64 + mi * 16 + rrow + i;
        float v = acc[mi][ni][i] + bv;
        if constexpr (std::is_same<OutT, float>::value)
          Cout[(long)grow * N + gcol] = v;
        else
          Cout[(long)grow * N + gcol] = (bf16)v;
      }
    }
  }
}

// ---------------- causal flash attention ----------------
// grid (T/128, B*H), 256 thr. Wave w owns q rows [q0+32w, q0+32w+32).
// Double-buffered K/V staging (2-phase pipeline), KBLK=64.
__global__ __launch_bounds__(256) void flash_kernel(
    const bf16* __restrict__ Y, const bf16* __restrict__ Vt,
    bf16* __restrict__ O) {
  __shared__ __align__(16) bf16 Klds[2][64 * 64];   // [buf][krow][d], swizzled
  __shared__ __align__(16) bf16 Vlds[2][64 * 64];   // [buf][d][kk], swizzled
  __shared__ __align__(16) bf16 Plds[4][32][72];    // per-wave, 16B-aligned rows
  const int tid = threadIdx.x;
  const int w = tid >> 6, l = tid & 63;
  const int bx = (int)gridDim.x - 1 - (int)blockIdx.x;  // heavy blocks first
  const int q0 = bx * 128;
  const int bh = blockIdx.y;
  const int b = bh >> 4, h = bh & 15;
  const bf16* Qbase = Y + (long)(b * Tc + q0) * N3 + h * 64;
  const bf16* Kbase = Y + (long)(b * Tc) * N3 + Cc + h * 64;
  const bf16* Vbase = Vt + (long)bh * 64 * Tc;
  const int rbase = w * 32;  // wave's rows: q0+rbase .. +31

  // Q fragments: aq[rowfrag][kchunk]
  bf16x8 aq[2][2];
#pragma unroll
  for (int rf = 0; rf < 2; rf++) {
    const bf16* qp =
        Qbase + (long)(rbase + rf * 16 + (l & 15)) * N3 + (l >> 4) * 8;
    aq[rf][0] = *(const bf16x8*)(qp);
    aq[rf][1] = *(const bf16x8*)(qp + 32);
  }
  f32x4 o[2][4] = {};
  float mrun[2][4], lrun[2][4];
#pragma unroll
  for (int rf = 0; rf < 2; rf++)
#pragma unroll
    for (int i = 0; i < 4; i++) {
      mrun[rf][i] = -__builtin_inff();
      lrun[rf][i] = 0.f;
    }

  const int srow = tid >> 3, schunk = tid & 7;
  const int swz = (schunk ^ (srow & 7)) * 8;  // pre-swizzled source chunk
  const int wbase = w * 1024;
  char* KldsB = (char*)Klds;
  char* VldsB = (char*)Vlds;
  const int nkt = 2 * bx + 2;

  auto stage = [&](int buf, int kt0) {
    char* kd = KldsB + buf * 8192 + wbase;
    char* vd = VldsB + buf * 8192 + wbase;
    GLOAD(Kbase + (long)(kt0 + srow) * N3 + swz, kd);
    GLOAD(Kbase + (long)(kt0 + srow + 32) * N3 + swz, kd + 4096);
    GLOAD(Vbase + (long)srow * Tc + kt0 + swz, vd);
    GLOAD(Vbase + (long)(srow + 32) * Tc + kt0 + swz, vd + 4096);
  };

  stage(0, 0);
  __syncthreads();  // drains vmcnt before first compute

  for (int kt = 0; kt < nkt; kt++) {
    const int kt0 = kt * 64;
    if (kt + 1 < nkt) stage((kt + 1) & 1, kt0 + 64);  // prefetch next tile
    const char* kb = KldsB + (kt & 1) * 8192;
    const char* vb = VldsB + (kt & 1) * 8192;

    if (kt0 <= q0 + rbase + 31) {  // wave has unmasked cols in this tile
      // S = Q K^T  -> s[rf][cb]
      f32x4 s[2][4];
#pragma unroll
      for (int cb = 0; cb < 4; cb++) {
        f32x4 a0 = {}, a1 = {};
        const int kr = cb * 16 + (l & 15);
#pragma unroll
        for (int dc = 0; dc < 2; dc++) {
          int c = dc * 4 + (l >> 4);
          bf16x8 bk = *(const bf16x8*)(kb + kr * 128 + ((c ^ (kr & 7)) * 16));
          a0 = __builtin_amdgcn_mfma_f32_16x16x32_bf16(aq[0][dc], bk, a0, 0, 0, 0);
          a1 = __builtin_amdgcn_mfma_f32_16x16x32_bf16(aq[1][dc], bk, a1, 0, 0, 0);
        }
        s[0][cb] = a0;
        s[1][cb] = a1;
      }
      const bool need_mask = (kt0 + 63 > q0 + rbase);
#pragma unroll
      for (int rf = 0; rf < 2; rf++)
#pragma unroll
        for (int cb = 0; cb < 4; cb++)
#pragma unroll
          for (int i = 0; i < 4; i++) {
            float v = s[rf][cb][i] * 0.125f;
            if (need_mask) {
              int qrow = q0 + rbase + rf * 16 + (l >> 4) * 4 + i;
              int kcol = kt0 + cb * 16 + (l & 15);
              if (kcol > qrow) v = -__builtin_inff();
            }
            s[rf][cb][i] = v;
          }
      // online softmax + P store
#pragma unroll
      for (int rf = 0; rf < 2; rf++)
#pragma unroll
        for (int i = 0; i < 4; i++) {
          float pm = fmaxf(fmaxf(s[rf][0][i], s[rf][1][i]),
                           fmaxf(s[rf][2][i], s[rf][3][i]));
#pragma unroll
          for (int msk = 1; msk < 16; msk <<= 1)
            pm = fmaxf(pm, __shfl_xor(pm, msk));
          float mnew = fmaxf(mrun[rf][i], pm);
          float factor = __expf(mrun[rf][i] - mnew);
          mrun[rf][i] = mnew;
          float ps = 0.f;
#pragma unroll
          for (int cb = 0; cb < 4; cb++) {
            float p = __expf(s[rf][cb][i] - mnew);
            s[rf][cb][i] = p;
            ps += p;
          }
#pragma unroll
          for (int msk = 1; msk < 16; msk <<= 1) ps += __shfl_xor(ps, msk);
          lrun[rf][i] = lrun[rf][i] * factor + ps;
#pragma unroll
          for (int nb = 0; nb < 4; nb++) o[rf][nb][i] *= factor;
          int prow = rf * 16 + (l >> 4) * 4 + i;
#pragma unroll
          for (int cb = 0; cb < 4; cb++)
            Plds[w][prow][cb * 16 + (l & 15)] = (bf16)s[rf][cb][i];
        }
      // O += P V
#pragma unroll
      for (int kc = 0; kc < 2; kc++) {
        bf16x8 pa0 = *(const bf16x8*)&Plds[w][l & 15][kc * 32 + (l >> 4) * 8];
        bf16x8 pa1 =
            *(const bf16x8*)&Plds[w][16 + (l & 15)][kc * 32 + (l >> 4) * 8];
#pragma unroll
        for (int nb = 0; nb < 4; nb++) {
          int dr = nb * 16 + (l & 15);
          int c = kc * 4 + (l >> 4);
          bf16x8 vbf = *(const bf16x8*)(vb + dr * 128 + ((c ^ (dr & 7)) * 16));
          o[0][nb] = __builtin_amdgcn_mfma_f32_16x16x32_bf16(pa0, vbf, o[0][nb], 0, 0, 0);
          o[1][nb] = __builtin_amdgcn_mfma_f32_16x16x32_bf16(pa1, vbf, o[1][nb], 0, 0, 0);
        }
      }
    }
    __syncthreads();  // drains vmcnt: next buffer ready, this buffer reusable
  }
  // epilogue
#pragma unroll
  for (int rf = 0; rf < 2; rf++)
#pragma unroll
    for (int i = 0; i < 4; i++) {
      float inv = 1.f / lrun[rf][i];
      int grow = b * Tc + q0 + rbase + rf * 16 + (l >> 4) * 4 + i;
#pragma unroll
      for (int nb = 0; nb < 4; nb++) {
        int gcol = h * 64 + nb * 16 + (l & 15);
        O[(long)grow * Cc + gcol] = (bf16)(o[rf][nb][i] * inv);
      }
    }
}

extern "C" void kernel_launch(void* const* d_in, const int* in_sizes, int n_in,
                              void* d_out, int out_size, void* d_ws,
                              size_t ws_size, hipStream_t stream) {
  const float* x = (const float*)d_in[0];
  const float* qkv_w = (const float*)d_in[1];
  const float* qkv_b = (const float*)d_in[2];
  const float* out_w = (const float*)d_in[3];
  const float* out_b = (const float*)d_in[4];
  float* out = (float*)d_out;
  char* ws = (char*)d_ws;
  bf16* xb = (bf16*)(ws);                            // 16 MiB (x bf16)
  bf16* Obuf = (bf16*)(ws);                          // reuse after GEMM1
  bf16* wqkvT = (bf16*)(ws + (16ull << 20));         // 6 MiB
  bf16* woT = (bf16*)(ws + (22ull << 20));           // 2 MiB
  bf16* Ybuf = (bf16*)(ws + (24ull << 20));          // 48 MiB
  bf16* Vtb = (bf16*)(ws + (72ull << 20));           // 16 MiB  (total 88 MiB)

  cast_bf16_kernel<<<2048, 256, 0, stream>>>(x, xb, Mrows * Cc / 8);
  transpose_cast_kernel<<<dim3(N3 / 32, Cc / 32), dim3(32, 8), 0, stream>>>(
      qkv_w, wqkvT, Cc, N3);
  transpose_cast_kernel<<<dim3(Cc / 32, Cc / 32), dim3(32, 8), 0, stream>>>(
      out_w, woT, Cc, Cc);
  gemm_bt_kernel<bf16><<<dim3(Mrows / 128, N3 / 128), 256, 0, stream>>>(
      xb, wqkvT, qkv_b, Ybuf, Mrows, N3, Cc);
  transpose_v_kernel<<<dim3(Tc / 32, 2, Bc * Hc), dim3(32, 8), 0, stream>>>(
      Ybuf, Vtb);
  flash_kernel<<<dim3(Tc / 128, Bc * Hc), 256, 0, stream>>>(Ybuf, Vtb, Obuf);
  gemm_bt_kernel<float><<<dim3(Mrows / 128, Cc / 128), 256, 0, stream>>>(
      Obuf, woT, out_b, out, Mrows, Cc, Cc);
}

// Round 4
// 278.372 us; speedup vs baseline: 1.5598x; 1.5598x over previous
//
#include <hip/hip_runtime.h>
#include <type_traits>

typedef __bf16 bf16;
typedef __attribute__((ext_vector_type(8))) __bf16 bf16x8;
typedef __attribute__((ext_vector_type(4))) float f32x4;
typedef __attribute__((ext_vector_type(16))) float f32x16;

constexpr int Bc = 4, Tc = 2048, Cc = 1024, Hc = 16;
constexpr int Mrows = Bc * Tc;   // 8192
constexpr int N3 = 3 * Cc;       // 3072

#define GLOAD(gp, lp)                                                          \
  __builtin_amdgcn_global_load_lds(                                           \
      (const __attribute__((address_space(1))) void*)(gp),                     \
      (__attribute__((address_space(3))) void*)(lp), 16, 0, 0)

__device__ __forceinline__ uint32_t pk2(float a, float b) {
  uint16_t x = __builtin_bit_cast(uint16_t, (bf16)a);
  uint16_t y = __builtin_bit_cast(uint16_t, (bf16)b);
  return (uint32_t)x | ((uint32_t)y << 16);
}

// ---------------- cast fp32 -> bf16, 8 elems/thread ----------------
__global__ __launch_bounds__(256) void cast_bf16_kernel(
    const float* __restrict__ in, bf16* __restrict__ out, int n8) {
  int i = blockIdx.x * blockDim.x + threadIdx.x;
  int stride = gridDim.x * blockDim.x;
  for (; i < n8; i += stride) {
    const float4* p = (const float4*)(in + (long)i * 8);
    float4 a = p[0], b = p[1];
    bf16x8 v;
    v[0] = (bf16)a.x; v[1] = (bf16)a.y; v[2] = (bf16)a.z; v[3] = (bf16)a.w;
    v[4] = (bf16)b.x; v[5] = (bf16)b.y; v[6] = (bf16)b.z; v[7] = (bf16)b.w;
    *(bf16x8*)(out + (long)i * 8) = v;
  }
}

// ---- transpose + cast: in[rows][cols] f32 -> out[cols][rows] bf16.
// Output rows < srows get multiplied by scale (used to fold 1/sqrt(D) into Wq).
__global__ __launch_bounds__(256) void transpose_cast_kernel(
    const float* __restrict__ in, bf16* __restrict__ out, int rows, int cols,
    float scale, int srows) {
  __shared__ float tile[32][33];
  int tx = threadIdx.x, ty = threadIdx.y;
  int r0 = blockIdx.y * 32, c0 = blockIdx.x * 32;
#pragma unroll
  for (int i = 0; i < 4; i++)
    tile[ty + 8 * i][tx] = in[(long)(r0 + ty + 8 * i) * cols + c0 + tx];
  __syncthreads();
#pragma unroll
  for (int i = 0; i < 4; i++) {
    int orow = c0 + ty + 8 * i;
    float v = tile[tx][ty + 8 * i];
    if (orow < srows) v *= scale;
    out[(long)orow * rows + r0 + tx] = (bf16)v;
  }
}

// ---- transpose V part of QKV: Y[.,2048+h*64+d] -> Vt[bh][d][t'] where
// t' quad-swaps bits 2,3 of (t&15) so PV fragments read b128 without lane
// exchange (MFMA contraction-slot bijection trick).
__global__ __launch_bounds__(256) void transpose_v_kernel(
    const bf16* __restrict__ Y, bf16* __restrict__ Vt) {
  __shared__ bf16 tile[32][33];
  int tx = threadIdx.x, ty = threadIdx.y;
  int t0 = blockIdx.x * 32;
  int d0 = blockIdx.y * 32;
  int bh = blockIdx.z;
  int b = bh >> 4, h = bh & 15;
  const bf16* src = Y + (long)(b * Tc) * N3 + 2 * Cc + h * 64;
#pragma unroll
  for (int i = 0; i < 4; i++)
    tile[ty + 8 * i][tx] = src[(long)(t0 + ty + 8 * i) * N3 + d0 + tx];
  __syncthreads();
  bf16* dst = Vt + (long)bh * 64 * Tc;
  int txp = (tx & 0x13) | ((tx & 4) << 1) | ((tx & 8) >> 1);  // quad swap
#pragma unroll
  for (int i = 0; i < 4; i++)
    dst[(long)(d0 + ty + 8 * i) * Tc + t0 + txp] = tile[tx][ty + 8 * i];
}

// ---------------- GEMM: C[M,N] = A[M,K](bf16) * Bt[N,K]^T + bias, m97 structure
// bias entries with col < sb get scaled by 0.125 (Q-bias fold).
template <typename OutT>
__global__ __launch_bounds__(256) void gemm_bt_kernel(
    const bf16* __restrict__ A, const bf16* __restrict__ Bt,
    const float* __restrict__ bias, OutT* __restrict__ Cout, int M, int N,
    int K, int sb) {
  __shared__ __align__(16) bf16 Alds[128 * 32];
  __shared__ __align__(16) bf16 Blds[128 * 32];
  const int tid = threadIdx.x;
  const int w = tid >> 6, l = tid & 63;
  const int m0 = blockIdx.x * 128, n0 = blockIdx.y * 128;
  const int wr = w >> 1, wc = w & 1;
  f32x4 acc[4][4] = {};
  const int arow = tid >> 2, achunk = tid & 3;
  const bf16* Ag = A + (long)(m0 + arow) * K + achunk * 8;
  const bf16* Bg = Bt + (long)(n0 + arow) * K + achunk * 8;
  char* AldsB = (char*)Alds;
  char* BldsB = (char*)Blds;
  const int wbase = w * 1024;  // wave-uniform LDS byte base

  for (int k0 = 0; k0 < K; k0 += 32) {
    __syncthreads();
    GLOAD(Ag + k0, AldsB + wbase);
    GLOAD(Ag + k0 + (long)64 * K, AldsB + wbase + 4096);
    GLOAD(Bg + k0, BldsB + wbase);
    GLOAD(Bg + k0 + (long)64 * K, BldsB + wbase + 4096);
    __syncthreads();
    const int kk = (l >> 4) * 8;
    bf16x8 af[4], bfr[4];
#pragma unroll
    for (int mi = 0; mi < 4; mi++)
      af[mi] = *(const bf16x8*)(AldsB +
                                ((wr * 64 + mi * 16 + (l & 15)) * 32 + kk) * 2);
#pragma unroll
    for (int ni = 0; ni < 4; ni++)
      bfr[ni] = *(const bf16x8*)(BldsB +
                                 ((wc * 64 + ni * 16 + (l & 15)) * 32 + kk) * 2);
#pragma unroll
    for (int mi = 0; mi < 4; mi++)
#pragma unroll
      for (int ni = 0; ni < 4; ni++)
        acc[mi][ni] = __builtin_amdgcn_mfma_f32_16x16x32_bf16(
            af[mi], bfr[ni], acc[mi][ni], 0, 0, 0);
  }
  const int rrow = (l >> 4) * 4, col = l & 15;
#pragma unroll
  for (int mi = 0; mi < 4; mi++) {
#pragma unroll
    for (int ni = 0; ni < 4; ni++) {
      int gcol = n0 + wc * 64 + ni * 16 + col;
      float bv = bias[gcol];
      if (gcol < sb) bv *= 0.125f;
#pragma unroll
      for (int i = 0; i < 4; i++) {
        int grow = m0 + wr * 64 + mi * 16 + rrow + i;
        float v = acc[mi][ni][i] + bv;
        if constexpr (std::is_same<OutT, float>::value)
          Cout[(long)grow * N + gcol] = v;
        else
          Cout[(long)grow * N + gcol] = (bf16)v;
      }
    }
  }
}

// ---------------- causal flash attention, swapped-operand 32x32x16 ----------
// grid (8, B*H), 256 thr, 4 waves. Each block runs TWO q-strips of 128 rows:
// strip bx and strip 15-bx (uniform 36 K-tiles per block). Wave w owns 32
// q-rows. Softmax is per-lane (lane's col = q-row) + one shfl_xor(32).
__global__ __launch_bounds__(256) void flash_kernel(
    const bf16* __restrict__ Y, const bf16* __restrict__ Vt,
    bf16* __restrict__ O) {
  __shared__ __align__(16) bf16 Klds[2][64 * 64];  // [buf][k][d], swizzled
  __shared__ __align__(16) bf16 Vlds[2][64 * 64];  // [buf][d][k'], swizzled
  const int tid = threadIdx.x;
  const int w = tid >> 6, l = tid & 63;
  const int ln = l & 31, hi = l >> 5;
  const int bh = blockIdx.y;
  const int b = bh >> 4, h = bh & 15;
  const bf16* Kbase = Y + (long)(b * Tc) * N3 + Cc + h * 64;
  const bf16* Vbase = Vt + (long)bh * 64 * Tc;

  const int srow = tid >> 3, schunk = tid & 7;
  const int swz = (schunk ^ (srow & 7)) * 8;  // pre-swizzled source chunk
  const int wbase = w * 1024;
  char* KldsB = (char*)Klds;
  char* VldsB = (char*)Vlds;

  auto stage = [&](int buf, int kt0) {
    char* kd = KldsB + buf * 8192 + wbase;
    char* vd = VldsB + buf * 8192 + wbase;
    GLOAD(Kbase + (long)(kt0 + srow) * N3 + swz, kd);
    GLOAD(Kbase + (long)(kt0 + srow + 32) * N3 + swz, kd + 4096);
    GLOAD(Vbase + (long)srow * Tc + kt0 + swz, vd);
    GLOAD(Vbase + (long)(srow + 32) * Tc + kt0 + swz, vd + 4096);
  };

#pragma unroll 1
  for (int sp = 0; sp < 2; sp++) {
    const int st = sp ? (15 - (int)blockIdx.x) : (int)blockIdx.x;
    const int q0 = st * 128;
    const int qmin = q0 + w * 32;       // wave's first q row
    const int qg = qmin + ln;           // this lane's q row
    const long grow = (long)(b * Tc) + qg;

    // Q fragments (pre-scaled by 0.125 via weight fold): B[n=q][d-slot]
    bf16x8 aq[4];
#pragma unroll
    for (int dc = 0; dc < 4; dc++)
      aq[dc] = *(const bf16x8*)(Y + grow * N3 + h * 64 + dc * 16 + hi * 8);

    f32x16 ot[2] = {};
    float mrun = -__builtin_inff(), lrun = 0.f;
    const int nkt = 2 * st + 2;

    stage(0, 0);
    __syncthreads();

    for (int kt = 0; kt < nkt; kt++) {
      const int kt0 = kt * 64;
      if (kt + 1 < nkt) stage((kt + 1) & 1, kt0 + 64);
      const char* kb = KldsB + (kt & 1) * 8192;
      const char* vb = VldsB + (kt & 1) * 8192;

      if (kt0 <= qmin + 31) {
        // S^T = K Q^T : col(lane)=q, rows=k-pos
        f32x16 s[2];
#pragma unroll
        for (int ks = 0; ks < 2; ks++) {
          f32x16 acc = {};
          const int krow = ks * 32 + ln;
          const int kswz = (krow & 7) << 4;
#pragma unroll
          for (int dc = 0; dc < 4; dc++) {
            bf16x8 ak =
                *(const bf16x8*)(kb + krow * 128 + ((dc * 32 + hi * 16) ^ kswz));
            acc = __builtin_amdgcn_mfma_f32_32x32x16_bf16(ak, aq[dc], acc, 0, 0, 0);
          }
          s[ks] = acc;
        }
        // causal mask (diagonal tiles only; wave-uniform predicate)
        if (kt0 + 63 > qmin) {
#pragma unroll
          for (int ks = 0; ks < 2; ks++)
#pragma unroll
            for (int r = 0; r < 16; r++) {
              int kg = kt0 + ks * 32 + (r & 3) + 8 * (r >> 2) + 4 * hi;
              if (kg > qg) s[ks][r] = -__builtin_inff();
            }
        }
        // per-lane online softmax (lane holds 32 of 64 cols; partner the rest)
        float tm = s[0][0];
#pragma unroll
        for (int ks = 0; ks < 2; ks++)
#pragma unroll
          for (int r = 0; r < 16; r++) tm = fmaxf(tm, s[ks][r]);
        tm = fmaxf(tm, __shfl_xor(tm, 32));
        float mnew = fmaxf(mrun, tm);
        float factor = __expf(mrun - mnew);
        float lsum = 0.f;
#pragma unroll
        for (int ks = 0; ks < 2; ks++)
#pragma unroll
          for (int r = 0; r < 16; r++) {
            float p = __expf(s[ks][r] - mnew);
            s[ks][r] = p;
            lsum += p;
          }
        lsum += __shfl_xor(lsum, 32);
        lrun = lrun * factor + lsum;
        mrun = mnew;
#pragma unroll
        for (int db = 0; db < 2; db++)
#pragma unroll
          for (int r = 0; r < 16; r++) ot[db][r] *= factor;
        // pack P to bf16 pairs (natural order feeds PV via k-permuted V)
        uint32_t pu[2][8];
#pragma unroll
        for (int ks = 0; ks < 2; ks++)
#pragma unroll
          for (int j = 0; j < 8; j++)
            pu[ks][j] = pk2(s[ks][2 * j], s[ks][2 * j + 1]);
        // O^T += V^T P^T  (col=q matches softmax lane)
#pragma unroll
        for (int ks = 0; ks < 2; ks++)
#pragma unroll
          for (int g = 0; g < 2; g++) {
            union { uint32_t u[4]; bf16x8 v; } pf;
            pf.u[0] = pu[ks][g * 4 + 0];
            pf.u[1] = pu[ks][g * 4 + 1];
            pf.u[2] = pu[ks][g * 4 + 2];
            pf.u[3] = pu[ks][g * 4 + 3];
#pragma unroll
            for (int db = 0; db < 2; db++) {
              const int vrow = db * 32 + ln;
              bf16x8 av = *(const bf16x8*)(
                  vb + vrow * 128 +
                  ((ks * 64 + g * 32 + hi * 16) ^ ((vrow & 7) << 4)));
              ot[db] = __builtin_amdgcn_mfma_f32_32x32x16_bf16(av, pf.v, ot[db],
                                                               0, 0, 0);
            }
          }
      }
      __syncthreads();
    }

    // epilogue: assemble contiguous d-octets via one lane-pair exchange
    const float sc = 1.f / lrun;
#pragma unroll
    for (int db = 0; db < 2; db++) {
      uint32_t u[8];
#pragma unroll
      for (int j = 0; j < 8; j++)
        u[j] = pk2(ot[db][2 * j] * sc, ot[db][2 * j + 1] * sc);
#pragma unroll
      for (int g = 0; g < 2; g++) {
        uint32_t a0 = u[g * 4 + 0], a1 = u[g * 4 + 1];
        uint32_t a2 = u[g * 4 + 2], a3 = u[g * 4 + 3];
        uint32_t x0 = hi ? a0 : a2, x1 = hi ? a1 : a3;
        uint32_t y0 = (uint32_t)__shfl_xor((int)x0, 32);
        uint32_t y1 = (uint32_t)__shfl_xor((int)x1, 32);
        union { uint32_t u[4]; bf16x8 v; } f;
        f.u[0] = hi ? y0 : a0;
        f.u[1] = hi ? y1 : a1;
        f.u[2] = hi ? a2 : y0;
        f.u[3] = hi ? a3 : y1;
        *(bf16x8*)(O + grow * Cc + h * 64 + db * 32 + g * 16 + hi * 8) = f.v;
      }
    }
  }
}

extern "C" void kernel_launch(void* const* d_in, const int* in_sizes, int n_in,
                              void* d_out, int out_size, void* d_ws,
                              size_t ws_size, hipStream_t stream) {
  const float* x = (const float*)d_in[0];
  const float* qkv_w = (const float*)d_in[1];
  const float* qkv_b = (const float*)d_in[2];
  const float* out_w = (const float*)d_in[3];
  const float* out_b = (const float*)d_in[4];
  float* out = (float*)d_out;
  char* ws = (char*)d_ws;
  bf16* xb = (bf16*)(ws);                            // 16 MiB (x bf16)
  bf16* Obuf = (bf16*)(ws);                          // reuse after GEMM1
  bf16* wqkvT = (bf16*)(ws + (16ull << 20));         // 6 MiB
  bf16* woT = (bf16*)(ws + (22ull << 20));           // 2 MiB
  bf16* Ybuf = (bf16*)(ws + (24ull << 20));          // 48 MiB
  bf16* Vtb = (bf16*)(ws + (72ull << 20));           // 16 MiB  (total 88 MiB)

  cast_bf16_kernel<<<2048, 256, 0, stream>>>(x, xb, Mrows * Cc / 8);
  transpose_cast_kernel<<<dim3(N3 / 32, Cc / 32), dim3(32, 8), 0, stream>>>(
      qkv_w, wqkvT, Cc, N3, 0.125f, Cc);
  transpose_cast_kernel<<<dim3(Cc / 32, Cc / 32), dim3(32, 8), 0, stream>>>(
      out_w, woT, Cc, Cc, 1.0f, 0);
  gemm_bt_kernel<bf16><<<dim3(Mrows / 128, N3 / 128), 256, 0, stream>>>(
      xb, wqkvT, qkv_b, Ybuf, Mrows, N3, Cc, Cc);
  transpose_v_kernel<<<dim3(Tc / 32, 2, Bc * Hc), dim3(32, 8), 0, stream>>>(
      Ybuf, Vtb);
  flash_kernel<<<dim3(8, Bc * Hc), 256, 0, stream>>>(Ybuf, Vtb, Obuf);
  gemm_bt_kernel<float><<<dim3(Mrows / 128, Cc / 128), 256, 0, stream>>>(
      Obuf, woT, out_b, out, Mrows, Cc, Cc, 0);
}